// Round 5
// baseline (199.662 us; speedup 1.0000x reference)
//
#include <hip/hip_runtime.h>
#include <cstdint>
#include <cstddef>

// out[8192,2048] = x[8192,2048] @ W[2048,2048]^T + b   (fp32 in/out)
// Round 5: m201-faithful 256x256 BK=64 8-phase-per-2-tiles schedule,
// st_16x32 LDS swizzle (involution), dbuf-2, per-tile vmcnt(0) with
// burst-at-head staging, setprio around MFMA, XCD-chunked block swizzle.

#define MM 8192
#define NN 2048
#define KK 2048

typedef __attribute__((ext_vector_type(8))) short bf16x8;
typedef __attribute__((ext_vector_type(4))) float f32x4;

__device__ __forceinline__ unsigned int f2bf(float f) {
  union { float f; unsigned u; } x; x.f = f;
  unsigned u = x.u;
  return (u + 0x7fffu + ((u >> 16) & 1u)) >> 16;  // RNE
}

__global__ void cvt_both_kernel(const float* __restrict__ x, const float* __restrict__ w,
                                unsigned short* __restrict__ xb, unsigned short* __restrict__ wb) {
  const int XCH = MM * KK / 8;
  const int TCH = XCH + NN * KK / 8;
  int idx = blockIdx.x * blockDim.x + threadIdx.x;
  int stride = gridDim.x * blockDim.x;
  for (int c = idx; c < TCH; c += stride) {
    const float* src; unsigned short* dst; int cc;
    if (c < XCH) { src = x; dst = xb; cc = c; }
    else         { src = w; dst = wb; cc = c - XCH; }
    float4 a = ((const float4*)src)[2 * cc];
    float4 b = ((const float4*)src)[2 * cc + 1];
    uint4 o;
    o.x = f2bf(a.x) | (f2bf(a.y) << 16);
    o.y = f2bf(a.z) | (f2bf(a.w) << 16);
    o.z = f2bf(b.x) | (f2bf(b.y) << 16);
    o.w = f2bf(b.z) | (f2bf(b.w) << 16);
    ((uint4*)dst)[cc] = o;
  }
}

// A: [M][K] bf16, B: [N][K] bf16 (B^T layout), C fp32 [M][N].
// 8 waves = 2(M) x 4(N); per-wave output 128x64; acc[8][4] f32x4.
// LDS: 2 dbuf slots x (A [256][64] + B [256][64]) bf16 = 128 KiB.
// Swizzle (st_16x32, involution): stored_byte = byte ^ (((byte>>9)&1)<<5).
// global_load_lds dest LINEAR; source carries the (self-inverse) swizzle.
__global__ __launch_bounds__(512, 2) void gemm_bf16_8ph(
    const unsigned short* __restrict__ A,
    const unsigned short* __restrict__ B,
    const float* __restrict__ bias,
    float* __restrict__ C) {
  constexpr int BM = 256, BN = 256, BK = 64;
  constexpr int NT  = KK / BK;      // 32 K-tiles
  constexpr int NIT = NT / 2;       // 16 iterations of 2 tiles
  constexpr int SLOT = BM * BK;     // 16384 shorts = 32 KiB per matrix slot
  extern __shared__ unsigned short smem[];
  unsigned short* sA = smem;            // 2 * SLOT
  unsigned short* sB = smem + 2 * SLOT; // 2 * SLOT

  const int tid  = threadIdx.x;
  const int lane = tid & 63;
  const int w    = tid >> 6;
  const int wr   = w >> 2;   // 0..1
  const int wc   = w & 3;    // 0..3

  // XCD-chunked bijective swizzle (256 blocks = 8 XCDs x 32).
  const int l    = blockIdx.x;
  const int lid  = (l & 7) * 32 + (l >> 3);
  const int brow = (lid >> 3) * BM;
  const int bcol = (lid & 7) * BN;

  // Staging: 4 chunks of 16B per thread per matrix per K-tile.
  // LDS dest linear at chunk c*16; logical byte = swz(c*16) (involution).
  const unsigned short* asrc[4];
  const unsigned short* bsrc[4];
  int dste[4];
#pragma unroll
  for (int k = 0; k < 4; ++k) {
    int c   = tid + 512 * k;
    int L   = c * 16;
    int Lb  = L ^ (((L >> 9) & 1) << 5);
    int r   = Lb >> 7;            // row in tile
    int col = (Lb & 127) >> 1;    // bf16 col in [0,64)
    asrc[k] = A + (size_t)(brow + r) * KK + col;
    bsrc[k] = B + (size_t)(bcol + r) * KK + col;
    dste[k] = c * 8;
  }

#define STAGE(KT, S) do {                                                           \
    _Pragma("unroll") for (int k = 0; k < 4; ++k) {                                 \
      __builtin_amdgcn_global_load_lds(                                             \
          (const __attribute__((address_space(1))) void*)(asrc[k] + (KT) * BK),     \
          (__attribute__((address_space(3))) void*)(sA + (S) * SLOT + dste[k]),     \
          16, 0, 0);                                                                \
      __builtin_amdgcn_global_load_lds(                                             \
          (const __attribute__((address_space(1))) void*)(bsrc[k] + (KT) * BK),     \
          (__attribute__((address_space(3))) void*)(sB + (S) * SLOT + dste[k]),     \
          16, 0, 0);                                                                \
    } } while (0)

  // Fragment read byte-offsets (kh=0); kh=1 adds +64 (bit9 unaffected).
  int a_off[8], b_off[4];
#pragma unroll
  for (int mi = 0; mi < 8; ++mi) {
    int row  = wr * 128 + mi * 16 + (lane & 15);
    int byte = row * 128 + (lane >> 4) * 16;
    a_off[mi] = byte ^ (((row >> 2) & 1) << 5);
  }
#pragma unroll
  for (int ni = 0; ni < 4; ++ni) {
    int row  = wc * 64 + ni * 16 + (lane & 15);
    int byte = row * 128 + (lane >> 4) * 16;
    b_off[ni] = byte ^ (((row >> 2) & 1) << 5);
  }

  f32x4 acc[8][4] = {};

  // Prologue: stage tile 0, publish.
  STAGE(0, 0);
  asm volatile("s_waitcnt vmcnt(0)" ::: "memory");
  __builtin_amdgcn_s_barrier();

#define LGKM0 do { asm volatile("s_waitcnt lgkmcnt(0)" ::: "memory");               \
                   __builtin_amdgcn_sched_barrier(0); } while (0)
#define MFMA16(ACCROW, AF, BF) do {                                                 \
    __builtin_amdgcn_s_setprio(1);                                                  \
    _Pragma("unroll") for (int mi = 0; mi < 4; ++mi)                                \
      _Pragma("unroll") for (int ni = 0; ni < 4; ++ni)                              \
        acc[(ACCROW) + mi][ni] = __builtin_amdgcn_mfma_f32_16x16x32_bf16(           \
            AF[mi], BF[ni], acc[(ACCROW) + mi][ni], 0, 0, 0);                       \
    __builtin_amdgcn_s_setprio(0); } while (0)

  // One K-tile = 4 phases: (kh0,m0-3)(kh0,m4-7)(kh1,m0-3)(kh1,m4-7).
  // Phase = {reads (+stage in ph1) ; barrier ; lgkm(0) ; 16 MFMA ; barrier}.
  // Tile-end: vmcnt(0) publishes next tile (loads issued ~3 phases earlier).
#define TILE(S, DOSTAGE, STT, DOVM) do {                                            \
    const char* _a = (const char*)(sA + (S) * SLOT);                                \
    const char* _b = (const char*)(sB + (S) * SLOT);                                \
    bf16x8 af[4], bf[4];                                                            \
    /* phase 1: kh0, m0-3; stage next tile */                                       \
    if (DOSTAGE) STAGE(STT, (STT) & 1);                                             \
    _Pragma("unroll") for (int i = 0; i < 4; ++i)                                   \
        af[i] = *(const bf16x8*)(_a + a_off[i]);                                    \
    _Pragma("unroll") for (int i = 0; i < 4; ++i)                                   \
        bf[i] = *(const bf16x8*)(_b + b_off[i]);                                    \
    __builtin_amdgcn_s_barrier(); LGKM0;                                            \
    MFMA16(0, af, bf);                                                              \
    __builtin_amdgcn_s_barrier();                                                   \
    /* phase 2: kh0, m4-7 */                                                        \
    _Pragma("unroll") for (int i = 0; i < 4; ++i)                                   \
        af[i] = *(const bf16x8*)(_a + a_off[4 + i]);                                \
    __builtin_amdgcn_s_barrier(); LGKM0;                                            \
    MFMA16(4, af, bf);                                                              \
    __builtin_amdgcn_s_barrier();                                                   \
    /* phase 3: kh1, m0-3 */                                                        \
    _Pragma("unroll") for (int i = 0; i < 4; ++i)                                   \
        af[i] = *(const bf16x8*)(_a + a_off[i] + 64);                               \
    _Pragma("unroll") for (int i = 0; i < 4; ++i)                                   \
        bf[i] = *(const bf16x8*)(_b + b_off[i] + 64);                               \
    __builtin_amdgcn_s_barrier(); LGKM0;                                            \
    MFMA16(0, af, bf);                                                              \
    __builtin_amdgcn_s_barrier();                                                   \
    /* phase 4: kh1, m4-7 */                                                        \
    _Pragma("unroll") for (int i = 0; i < 4; ++i)                                   \
        af[i] = *(const bf16x8*)(_a + a_off[4 + i] + 64);                           \
    __builtin_amdgcn_s_barrier(); LGKM0;                                            \
    MFMA16(4, af, bf);                                                              \
    if (DOVM) { asm volatile("s_waitcnt vmcnt(0)" ::: "memory"); }                  \
    __builtin_amdgcn_s_barrier();                                                   \
  } while (0)

  for (int it = 0; it < NIT; ++it) {
    TILE(0, 1, 2 * it + 1, 1);                                  // tile 2it
    TILE(1, (it < NIT - 1), 2 * it + 2, (it < NIT - 1));        // tile 2it+1
  }

#undef TILE
#undef MFMA16
#undef LGKM0
#undef STAGE

  // Epilogue. C/D layout: col = lane&15, row = (lane>>4)*4 + j (verified r1).
  const int ccol = lane & 15;
  const int crow = (lane >> 4) * 4;
#pragma unroll
  for (int ni = 0; ni < 4; ++ni) {
    float bv = bias[bcol + wc * 64 + ni * 16 + ccol];
#pragma unroll
    for (int mi = 0; mi < 8; ++mi) {
      size_t rowg = (size_t)brow + wr * 128 + mi * 16 + crow;
      float* cp = C + rowg * NN + bcol + wc * 64 + ni * 16 + ccol;
#pragma unroll
      for (int j = 0; j < 4; ++j)
        cp[(size_t)j * NN] = acc[mi][ni][j] + bv;
    }
  }
}

// Correct-but-slow fp32 fallback in case ws_size < 40MB (unlikely).
__global__ void gemm_fallback(const float* __restrict__ X, const float* __restrict__ W,
                              const float* __restrict__ bias, float* __restrict__ out) {
  __shared__ float xs[512];
  int row = blockIdx.y;
  int col = blockIdx.x * 256 + threadIdx.x;
  float s = 0.f;
  for (int k0 = 0; k0 < KK; k0 += 512) {
    for (int t = threadIdx.x; t < 512; t += 256) xs[t] = X[(size_t)row * KK + k0 + t];
    __syncthreads();
    for (int k = 0; k < 512; ++k) s += xs[k] * W[(size_t)col * KK + k0 + k];
    __syncthreads();
  }
  out[(size_t)row * NN + col] = s + bias[col];
}

extern "C" void kernel_launch(void* const* d_in, const int* in_sizes, int n_in,
                              void* d_out, int out_size, void* d_ws, size_t ws_size,
                              hipStream_t stream) {
  const float* x    = (const float*)d_in[0];
  const float* wgt  = (const float*)d_in[1];
  const float* bias = (const float*)d_in[2];
  float* out = (float*)d_out;

  const size_t need = ((size_t)MM * KK + (size_t)NN * KK) * sizeof(unsigned short);
  if (ws_size >= need) {
    unsigned short* xb = (unsigned short*)d_ws;
    unsigned short* wb = xb + (size_t)MM * KK;
    cvt_both_kernel<<<2048, 256, 0, stream>>>(x, wgt, xb, wb);

    constexpr int lds_bytes = 4 * (256 * 64) * 2;  // 128 KiB
    hipFuncSetAttribute((const void*)gemm_bf16_8ph,
                        hipFuncAttributeMaxDynamicSharedMemorySize, lds_bytes);
    gemm_bf16_8ph<<<dim3(256), 512, lds_bytes, stream>>>(xb, wb, bias, out);
  } else {
    dim3 grid(NN / 256, MM);
    gemm_fallback<<<grid, 256, 0, stream>>>(x, wgt, bias, out);
  }
}